// Round 1
// baseline (767.874 us; speedup 1.0000x reference)
//
#include <hip/hip_runtime.h>

namespace {

constexpr int H = 512;
constexpr int W = 512;
constexpr int HW = H * W;
constexpr int PPS = 8;    // planes per canny set
constexpr int NP = 16;    // total planes (2 sets x 8)
constexpr float PI_F = 3.14159265358979323846f;

__device__ __forceinline__ float hsw(float x) {
    float t = fminf(fmaxf(x + 3.0f, 0.0f), 6.0f);
    return x * t * (1.0f / 6.0f);
}

// monotonic float->uint key (total order incl. negatives)
__device__ __forceinline__ unsigned fkey(float x) {
    unsigned b = __float_as_uint(x);
    return b ^ ((unsigned)((int)b >> 31) | 0x80000000u);
}
__device__ __forceinline__ float fkeyinv(unsigned k) {
    unsigned b = (k & 0x80000000u) ? (k ^ 0x80000000u) : ~k;
    return __uint_as_float(b);
}

__device__ __forceinline__ const float* plane_ptr(const float* s1, const float* s2, int p) {
    return (p < PPS) ? (s1 + (size_t)p * HW) : (s2 + (size_t)(p - PPS) * HW);
}

__device__ __forceinline__ float zp(const float* f, int i, int j) {
    return (i >= 0 && i < H && j >= 0 && j < W) ? f[i * W + j] : 0.0f;
}

__device__ __forceinline__ void sobel_taps(const float* f, int i, int j, float& ex, float& ey) {
    float xmm = zp(f, i - 1, j - 1), xm0 = zp(f, i - 1, j), xmp = zp(f, i - 1, j + 1);
    float x0m = zp(f, i, j - 1), x0p = zp(f, i, j + 1);
    float xpm = zp(f, i + 1, j - 1), xp0 = zp(f, i + 1, j), xpp = zp(f, i + 1, j + 1);
    ex = (xmp - xmm) + 2.0f * (x0p - x0m) + (xpp - xpm);
    ey = (xpm + 2.0f * xp0 + xpp) - (xmm + 2.0f * xm0 + xmp);
}

__global__ void K_init(unsigned* hist, unsigned* prefix, int* krem,
                       unsigned* mxkey, unsigned* rmaxkey, unsigned* rminkey) {
    int t = threadIdx.x;
    for (int i = t; i < NP * 256; i += 256) hist[i] = 0;
    if (t < NP) { prefix[t] = 0; krem[t] = (HW - 1) / 2; }
    if (t < 2) { mxkey[t] = 0; rmaxkey[t] = 0; rminkey[t] = 0; }
}

// w = exp(-(Gx^2+Gy^2)/(2*k^2)), gradients with replicate (clip) boundary
__global__ void K_w(const float* __restrict__ s1, const float* __restrict__ s2,
                    float* __restrict__ wout) {
    int j = blockIdx.x * 64 + threadIdx.x;
    int i = blockIdx.y * 4 + threadIdx.y;
    int p = blockIdx.z;
    const float* f = plane_ptr(s1, s2, p);
    int im = max(i - 1, 0), ip = min(i + 1, H - 1);
    int jm = max(j - 1, 0), jp = min(j + 1, W - 1);
    float gx = 0.5f * (f[ip * W + j] - f[im * W + j]);
    float gy = 0.5f * (f[i * W + jp] - f[i * W + jm]);
    wout[(size_t)p * HW + i * W + j] = expf(-(gx * gx + gy * gy) * (1.0f / 200.0f));
}

// f_new = sum_{a,b} f[clip(i+a),clip(j+b)] * w[clip..] / max(sum w, 1e-8)
__global__ void K_f(const float* __restrict__ s1, const float* __restrict__ s2,
                    const float* __restrict__ wbuf, float* __restrict__ fout) {
    int j = blockIdx.x * 64 + threadIdx.x;
    int i = blockIdx.y * 4 + threadIdx.y;
    int p = blockIdx.z;
    const float* f = plane_ptr(s1, s2, p);
    const float* w = wbuf + (size_t)p * HW;
    float num = 0.0f, den = 0.0f;
    for (int a = -1; a <= 1; a++) {
        int r = min(max(i + a, 0), H - 1);
        for (int b = -1; b <= 1; b++) {
            int c = min(max(j + b, 0), W - 1);
            float fv = f[r * W + c];
            float wv = w[r * W + c];
            num += fv * wv;
            den += wv;
        }
    }
    fout[(size_t)p * HW + i * W + j] = num / fmaxf(den, 1e-8f);
}

// median pass 0: compute sob(blurred), store it, histogram top 8 bits
__global__ void K_med0(const float* __restrict__ blur, float* __restrict__ sob,
                       unsigned* __restrict__ hist) {
    __shared__ unsigned sh[256];
    int t = threadIdx.x;
    int p = blockIdx.y;
    sh[t] = 0;
    __syncthreads();
    const float* f = blur + (size_t)p * HW;
    int base = blockIdx.x * 4096;
    for (int r = 0; r < 16; r++) {
        int ij = base + r * 256 + t;
        int i = ij >> 9, j = ij & 511;
        float ex, ey;
        sobel_taps(f, i, j, ex, ey);
        float s = 0.5f * fabsf(ex) + 0.5f * fabsf(ey);
        sob[(size_t)p * HW + ij] = s;
        unsigned b = __float_as_uint(s);
        atomicAdd(&sh[(b >> 24) & 255], 1u);
    }
    __syncthreads();
    if (sh[t]) atomicAdd(&hist[p * 256 + t], sh[t]);
}

// median passes 1..3: filter by prefix, histogram next 8 bits
__global__ void K_medN(const float* __restrict__ sob, unsigned* __restrict__ hist,
                       const unsigned* __restrict__ prefix, int shift) {
    __shared__ unsigned sh[256];
    __shared__ unsigned pfx;
    int t = threadIdx.x;
    int p = blockIdx.y;
    sh[t] = 0;
    if (t == 0) pfx = prefix[p];
    __syncthreads();
    unsigned himask = 0xFFFFFFFFu << (shift + 8);
    int base = blockIdx.x * 4096;
    for (int r = 0; r < 16; r++) {
        int ij = base + r * 256 + t;
        unsigned b = __float_as_uint(sob[(size_t)p * HW + ij]);
        if ((b & himask) == pfx) atomicAdd(&sh[(b >> shift) & 255], 1u);
    }
    __syncthreads();
    if (sh[t]) atomicAdd(&hist[p * 256 + t], sh[t]);
}

__global__ void K_scan(unsigned* hist, unsigned* prefix, int* krem, int shift) {
    int t = threadIdx.x;
    if (t < NP) {
        int k = krem[t];
        unsigned* hp = hist + t * 256;
        int cum = 0;
        int b = 0;
        for (; b < 256; b++) {
            int c = (int)hp[b];
            if (cum + c > k) break;
            cum += c;
        }
        if (b > 255) b = 255;
        prefix[t] |= ((unsigned)b) << shift;
        krem[t] = k - cum;
    }
    __syncthreads();
    for (int i = t; i < NP * 256; i += blockDim.x) hist[i] = 0;
}

__global__ void K_thresh(const unsigned* prefix, const float* sg1, const float* ew1,
                         const float* sg2, const float* ew2,
                         float* lowv, float* highv, float* wgtv) {
    int s = threadIdx.x;
    if (s < 2) {
        float med = 0.0f;
        for (int p = 0; p < PPS; p++) med += __uint_as_float(prefix[s * PPS + p]);
        med *= 0.125f;
        float sgin = (s == 0) ? sg1[0] : sg2[0];
        float ewin = (s == 0) ? ew1[0] : ew2[0];
        float sigm = 1.0f / (1.0f + expf(-sgin));   // sigmoid(sigma_in)
        float sig = 1.0f - sigm;                    // sigma passed to canny
        lowv[s] = fminf(fmaxf((1.0f - sig) * med, 0.001f), 1.0f);
        highv[s] = fminf(fmaxf((1.0f + sig) * med, 0.001f), 1.0f);
        wgtv[s] = 1.0f / (1.0f + expf(-ewin));
    }
}

// 4 direction convs (zero pad) -> mag, ang
__global__ void K_derivs(const float* __restrict__ blur, float* __restrict__ mag,
                         float* __restrict__ ang) {
    int j = blockIdx.x * 64 + threadIdx.x;
    int i = blockIdx.y * 4 + threadIdx.y;
    int p = blockIdx.z;
    const float* f = blur + (size_t)p * HW;
    float xmm = zp(f, i - 1, j - 1), xm0 = zp(f, i - 1, j), xmp = zp(f, i - 1, j + 1);
    float x0m = zp(f, i, j - 1), x0p = zp(f, i, j + 1);
    float xpm = zp(f, i + 1, j - 1), xp0 = zp(f, i + 1, j), xpp = zp(f, i + 1, j + 1);
    float ex = (xmp - xmm) + 2.0f * (x0p - x0m) + (xpp - xpm);
    float ey = (xpm + 2.0f * xp0 + xpp) - (xmm + 2.0f * xm0 + xmp);
    float e45 = -2.0f * xmm - xm0 - x0m + x0p + xp0 + 2.0f * xpp;
    float e135 = xm0 + 2.0f * xmp - x0m + x0p - 2.0f * xpm - xp0;
    float m = sqrtf(ex * ex + ey * ey + e45 * e45 + e135 * e135);
    float a = atan2f(ey, ex);
    a = fmodf(a, PI_F);
    if (a < 0.0f) a += PI_F;
    size_t idx = (size_t)p * HW + i * W + j;
    mag[idx] = m;
    ang[idx] = a;
}

__global__ void K_nms(const float* __restrict__ mag, const float* __restrict__ ang,
                      float* __restrict__ sup, unsigned* __restrict__ mxkey) {
    int j = blockIdx.x * 64 + threadIdx.x;
    int i = blockIdx.y * 4 + threadIdx.y;
    int p = blockIdx.z;
    const float* mp = mag + (size_t)p * HW;
    float m0 = mp[i * W + j];
    float a = ang[(size_t)p * HW + i * W + j];

    const float dirs[4] = {0.0f, 0.785398163397448f, 1.570796326794897f, 2.356194490192345f};
    float L[4];
    for (int t = 0; t < 4; t++) {
        float d = fabsf(a - dirs[t]);
        float mm = fminf(d, PI_F - d);
        L[t] = mm * (-100.0f);
    }
    float lm = fmaxf(fmaxf(L[0], L[1]), fmaxf(L[2], L[3]));
    float e0 = expf(L[0] - lm), e1 = expf(L[1] - lm), e2 = expf(L[2] - lm), e3 = expf(L[3] - lm);
    float esum = e0 + e1 + e2 + e3;
    float dw[4] = {e0 / esum, e1 / esum, e2 / esum, e3 / esum};

    int im = max(i - 1, 0), ip = min(i + 1, H - 1);
    int jm = max(j - 1, 0), jp = min(j + 1, W - 1);
    float n1s[4] = {mp[i * W + jm], mp[im * W + jm], mp[im * W + j], mp[im * W + jp]};
    float n2s[4] = {mp[i * W + jp], mp[ip * W + jp], mp[ip * W + j], mp[ip * W + jm]};

    float s = 0.0f;
    for (int t = 0; t < 4; t++) {
        float n1 = n1s[t], n2 = n2s[t];
        float mx3 = fmaxf(m0, fmaxf(n1, n2));
        float a0 = expf((m0 - mx3) * 10.0f);
        float a1 = expf((n1 - mx3) * 10.0f);
        float a2 = expf((n2 - mx3) * 10.0f);
        float sw = a0 / (a0 + a1 + a2);
        s += m0 * sw * dw[t];
    }
    sup[(size_t)p * HW + i * W + j] = s;

    // block-level max then one atomic (sup >= 0 so raw bits order as uint)
    __shared__ float red[256];
    int tid = threadIdx.y * 64 + threadIdx.x;
    red[tid] = s;
    __syncthreads();
    for (int sft = 128; sft > 0; sft >>= 1) {
        if (tid < sft) red[tid] = fmaxf(red[tid], red[tid + sft]);
        __syncthreads();
    }
    if (tid == 0) atomicMax(&mxkey[p >> 3], __float_as_uint(red[0]));
}

__global__ void K_result(const float* __restrict__ sup, const float* __restrict__ im1,
                         const float* __restrict__ im2, const float* __restrict__ lowv,
                         const float* __restrict__ highv, const float* __restrict__ wgtv,
                         const unsigned* __restrict__ mxkey, float* __restrict__ res,
                         unsigned* __restrict__ rmaxkey, unsigned* __restrict__ rminkey) {
    int j = blockIdx.x * 64 + threadIdx.x;
    int i = blockIdx.y * 4 + threadIdx.y;
    int p = blockIdx.z;
    int s = p >> 3;
    float mx = __uint_as_float(mxkey[s]);
    float inv = 1.0f / ((mx > 0.0f) ? mx : 1.0f);
    float lo = lowv[s], hi = highv[s], wg = wgtv[s];
    const float* sp = sup + (size_t)p * HW;

    float sn0 = sp[i * W + j] * inv;
    float Sh0 = hsw(sn0 - hi);
    float Sl0 = hsw(sn0 - lo);
    float dil = 0.0f;
    for (int a = -1; a <= 1; a++) {
        int r = i + a;
        if (r < 0 || r >= H) continue;
        for (int b = -1; b <= 1; b++) {
            int c = j + b;
            if (c < 0 || c >= W) continue;
            dil += hsw(sp[r * W + c] * inv - hi);
        }
    }
    float pre = sn0 * (Sh0 + Sl0) + dil * Sl0 * (1.0f - Sh0);

    const float* op = plane_ptr(im1, im2, p);
    float exo, eyo;
    sobel_taps(op, i, j, exo, eyo);
    float sob = 0.5f * fabsf(exo) + 0.5f * fabsf(eyo);

    float r = (1.0f - wg) * pre + wg * sob;
    res[(size_t)p * HW + i * W + j] = r;

    __shared__ float rmx[256], rmn[256];
    int tid = threadIdx.y * 64 + threadIdx.x;
    rmx[tid] = r;
    rmn[tid] = r;
    __syncthreads();
    for (int sft = 128; sft > 0; sft >>= 1) {
        if (tid < sft) {
            rmx[tid] = fmaxf(rmx[tid], rmx[tid + sft]);
            rmn[tid] = fminf(rmn[tid], rmn[tid + sft]);
        }
        __syncthreads();
    }
    if (tid == 0) {
        atomicMax(&rmaxkey[s], fkey(rmx[0]));
        atomicMax(&rminkey[s], ~fkey(rmn[0]));
    }
}

__global__ void K_final(const float* __restrict__ res, const unsigned* __restrict__ rmaxkey,
                        const unsigned* __restrict__ rminkey, float* __restrict__ out) {
    int j = blockIdx.x * 64 + threadIdx.x;
    int i = blockIdx.y * 4 + threadIdx.y;
    int p = blockIdx.z;  // 0..7
    float mx1 = fkeyinv(rmaxkey[0]), mn1 = fkeyinv(~rminkey[0]);
    float mx2 = fkeyinv(rmaxkey[1]), mn2 = fkeyinv(~rminkey[1]);
    size_t idx = (size_t)p * HW + i * W + j;
    float r1 = res[idx];
    float r2 = res[(size_t)(p + PPS) * HW + i * W + j];
    float m1 = (r1 - mn1) / (mx1 - mn1);
    float m2 = (r2 - mn2) / (mx2 - mn2);
    out[idx] = m1 + m2 - 2.0f * m1 * m2;               // 1 - f
    out[(size_t)PPS * HW + idx] = m1;
    out[(size_t)2 * PPS * HW + idx] = m2;
}

}  // namespace

extern "C" void kernel_launch(void* const* d_in, const int* in_sizes, int n_in,
                              void* d_out, int out_size, void* d_ws, size_t ws_size,
                              hipStream_t stream) {
    const float* img1 = (const float*)d_in[0];
    const float* img2 = (const float*)d_in[1];
    const float* sg1 = (const float*)d_in[2];
    const float* ew1 = (const float*)d_in[3];
    const float* sg2 = (const float*)d_in[4];
    const float* ew2 = (const float*)d_in[5];
    float* out = (float*)d_out;

    float* A = (float*)d_ws;
    float* B = A + (size_t)NP * HW;
    float* C = B + (size_t)NP * HW;
    unsigned* hist = (unsigned*)(C + (size_t)NP * HW);
    unsigned* prefix = hist + NP * 256;
    int* krem = (int*)(prefix + NP);
    unsigned* mxkey = (unsigned*)(krem + NP);
    unsigned* rmaxkey = mxkey + 2;
    unsigned* rminkey = rmaxkey + 2;
    float* lowv = (float*)(rminkey + 2);
    float* highv = lowv + 2;
    float* wgtv = highv + 2;

    dim3 blk(64, 4, 1);
    dim3 grd(W / 64, H / 4, NP);
    dim3 grd8(W / 64, H / 4, PPS);
    dim3 mblk(256, 1, 1);
    dim3 mgrd(64, NP, 1);

    K_init<<<dim3(1), dim3(256), 0, stream>>>(hist, prefix, krem, mxkey, rmaxkey, rminkey);

    // adaptive smoothing: 3 iterations, ping-pong  in->A, A->B, B->A
    K_w<<<grd, blk, 0, stream>>>(img1, img2, C);
    K_f<<<grd, blk, 0, stream>>>(img1, img2, C, A);
    K_w<<<grd, blk, 0, stream>>>(A, A + (size_t)PPS * HW, C);
    K_f<<<grd, blk, 0, stream>>>(A, A + (size_t)PPS * HW, C, B);
    K_w<<<grd, blk, 0, stream>>>(B, B + (size_t)PPS * HW, C);
    K_f<<<grd, blk, 0, stream>>>(B, B + (size_t)PPS * HW, C, A);   // blurred -> A

    // exact lower-median of sob(blurred) per plane via 4-pass radix select
    K_med0<<<mgrd, mblk, 0, stream>>>(A, B, hist);                  // sob -> B
    K_scan<<<dim3(1), dim3(256), 0, stream>>>(hist, prefix, krem, 24);
    K_medN<<<mgrd, mblk, 0, stream>>>(B, hist, prefix, 16);
    K_scan<<<dim3(1), dim3(256), 0, stream>>>(hist, prefix, krem, 16);
    K_medN<<<mgrd, mblk, 0, stream>>>(B, hist, prefix, 8);
    K_scan<<<dim3(1), dim3(256), 0, stream>>>(hist, prefix, krem, 8);
    K_medN<<<mgrd, mblk, 0, stream>>>(B, hist, prefix, 0);
    K_scan<<<dim3(1), dim3(256), 0, stream>>>(hist, prefix, krem, 0);
    K_thresh<<<dim3(1), dim3(64), 0, stream>>>(prefix, sg1, ew1, sg2, ew2, lowv, highv, wgtv);

    // gradients -> mag(B), ang(C); NMS -> sup(A); result -> B; final -> out
    K_derivs<<<grd, blk, 0, stream>>>(A, B, C);
    K_nms<<<grd, blk, 0, stream>>>(B, C, A, mxkey);
    K_result<<<grd, blk, 0, stream>>>(A, img1, img2, lowv, highv, wgtv, mxkey, B, rmaxkey, rminkey);
    K_final<<<grd8, blk, 0, stream>>>(B, rmaxkey, rminkey, out);
}

// Round 2
// 306.150 us; speedup vs baseline: 2.5082x; 2.5082x over previous
//
#include <hip/hip_runtime.h>

namespace {

constexpr int H = 512;
constexpr int W = 512;
constexpr int HW = H * W;
constexpr int PPS = 8;    // planes per canny set
constexpr int NP = 16;    // total planes (2 sets x 8)
constexpr int BLOCKS_PER_PLANE = (W / 64) * (H / 4);   // 1024
constexpr int NBLK = BLOCKS_PER_PLANE * NP;            // 16384
constexpr float PI_F = 3.14159265358979323846f;

__device__ __forceinline__ float hsw(float x) {
    float t = fminf(fmaxf(x + 3.0f, 0.0f), 6.0f);
    return x * t * (1.0f / 6.0f);
}

__device__ __forceinline__ const float* plane_ptr(const float* s1, const float* s2, int p) {
    return (p < PPS) ? (s1 + (size_t)p * HW) : (s2 + (size_t)(p - PPS) * HW);
}

__device__ __forceinline__ float zp(const float* f, int i, int j) {
    return (i >= 0 && i < H && j >= 0 && j < W) ? f[i * W + j] : 0.0f;
}

__device__ __forceinline__ void sobel_taps(const float* f, int i, int j, float& ex, float& ey) {
    float xmm = zp(f, i - 1, j - 1), xm0 = zp(f, i - 1, j), xmp = zp(f, i - 1, j + 1);
    float x0m = zp(f, i, j - 1), x0p = zp(f, i, j + 1);
    float xpm = zp(f, i + 1, j - 1), xp0 = zp(f, i + 1, j), xpp = zp(f, i + 1, j + 1);
    ex = (xmp - xmm) + 2.0f * (x0p - x0m) + (xpp - xpm);
    ey = (xpm + 2.0f * xp0 + xpp) - (xmm + 2.0f * xm0 + xmp);
}

__global__ void K_init(unsigned* hist, unsigned* prefix, int* krem) {
    int t = threadIdx.x;
    for (int i = t; i < NP * 256; i += 256) hist[i] = 0;
    if (t < NP) { prefix[t] = 0; krem[t] = (HW - 1) / 2; }
}

// w = exp(-(Gx^2+Gy^2)/(2*k^2)), gradients with replicate (clip) boundary
__global__ void K_w(const float* __restrict__ s1, const float* __restrict__ s2,
                    float* __restrict__ wout) {
    int j = blockIdx.x * 64 + threadIdx.x;
    int i = blockIdx.y * 4 + threadIdx.y;
    int p = blockIdx.z;
    const float* f = plane_ptr(s1, s2, p);
    int im = max(i - 1, 0), ip = min(i + 1, H - 1);
    int jm = max(j - 1, 0), jp = min(j + 1, W - 1);
    float gx = 0.5f * (f[ip * W + j] - f[im * W + j]);
    float gy = 0.5f * (f[i * W + jp] - f[i * W + jm]);
    wout[(size_t)p * HW + i * W + j] = expf(-(gx * gx + gy * gy) * (1.0f / 200.0f));
}

// f_new = sum_{a,b} f[clip(i+a),clip(j+b)] * w[clip..] / max(sum w, 1e-8)
__global__ void K_f(const float* __restrict__ s1, const float* __restrict__ s2,
                    const float* __restrict__ wbuf, float* __restrict__ fout) {
    int j = blockIdx.x * 64 + threadIdx.x;
    int i = blockIdx.y * 4 + threadIdx.y;
    int p = blockIdx.z;
    const float* f = plane_ptr(s1, s2, p);
    const float* w = wbuf + (size_t)p * HW;
    float num = 0.0f, den = 0.0f;
    for (int a = -1; a <= 1; a++) {
        int r = min(max(i + a, 0), H - 1);
        for (int b = -1; b <= 1; b++) {
            int c = min(max(j + b, 0), W - 1);
            float fv = f[r * W + c];
            float wv = w[r * W + c];
            num += fv * wv;
            den += wv;
        }
    }
    fout[(size_t)p * HW + i * W + j] = num / fmaxf(den, 1e-8f);
}

// median pass 0: compute sob(blurred), store it, histogram top 8 bits
__global__ void K_med0(const float* __restrict__ blur, float* __restrict__ sob,
                       unsigned* __restrict__ hist) {
    __shared__ unsigned sh[256];
    int t = threadIdx.x;
    int p = blockIdx.y;
    sh[t] = 0;
    __syncthreads();
    const float* f = blur + (size_t)p * HW;
    int base = blockIdx.x * 4096;
    for (int r = 0; r < 16; r++) {
        int ij = base + r * 256 + t;
        int i = ij >> 9, j = ij & 511;
        float ex, ey;
        sobel_taps(f, i, j, ex, ey);
        float s = 0.5f * fabsf(ex) + 0.5f * fabsf(ey);
        sob[(size_t)p * HW + ij] = s;
        unsigned b = __float_as_uint(s);
        atomicAdd(&sh[(b >> 24) & 255], 1u);
    }
    __syncthreads();
    if (sh[t]) atomicAdd(&hist[p * 256 + t], sh[t]);
}

// median passes 1..3: filter by prefix, histogram next 8 bits
__global__ void K_medN(const float* __restrict__ sob, unsigned* __restrict__ hist,
                       const unsigned* __restrict__ prefix, int shift) {
    __shared__ unsigned sh[256];
    __shared__ unsigned pfx;
    int t = threadIdx.x;
    int p = blockIdx.y;
    sh[t] = 0;
    if (t == 0) pfx = prefix[p];
    __syncthreads();
    unsigned himask = 0xFFFFFFFFu << (shift + 8);
    int base = blockIdx.x * 4096;
    for (int r = 0; r < 16; r++) {
        int ij = base + r * 256 + t;
        unsigned b = __float_as_uint(sob[(size_t)p * HW + ij]);
        if ((b & himask) == pfx) atomicAdd(&sh[(b >> shift) & 255], 1u);
    }
    __syncthreads();
    if (sh[t]) atomicAdd(&hist[p * 256 + t], sh[t]);
}

__global__ void K_scan(unsigned* hist, unsigned* prefix, int* krem, int shift) {
    int t = threadIdx.x;
    if (t < NP) {
        int k = krem[t];
        unsigned* hp = hist + t * 256;
        int cum = 0;
        int b = 0;
        for (; b < 256; b++) {
            int c = (int)hp[b];
            if (cum + c > k) break;
            cum += c;
        }
        if (b > 255) b = 255;
        prefix[t] |= ((unsigned)b) << shift;
        krem[t] = k - cum;
    }
    __syncthreads();
    for (int i = t; i < NP * 256; i += blockDim.x) hist[i] = 0;
}

__global__ void K_thresh(const unsigned* prefix, const float* sg1, const float* ew1,
                         const float* sg2, const float* ew2,
                         float* lowv, float* highv, float* wgtv) {
    int s = threadIdx.x;
    if (s < 2) {
        float med = 0.0f;
        for (int p = 0; p < PPS; p++) med += __uint_as_float(prefix[s * PPS + p]);
        med *= 0.125f;
        float sgin = (s == 0) ? sg1[0] : sg2[0];
        float ewin = (s == 0) ? ew1[0] : ew2[0];
        float sigm = 1.0f / (1.0f + expf(-sgin));   // sigmoid(sigma_in)
        float sig = 1.0f - sigm;                    // sigma passed to canny
        lowv[s] = fminf(fmaxf((1.0f - sig) * med, 0.001f), 1.0f);
        highv[s] = fminf(fmaxf((1.0f + sig) * med, 0.001f), 1.0f);
        wgtv[s] = 1.0f / (1.0f + expf(-ewin));
    }
}

// 4 direction convs (zero pad) -> mag, ang
__global__ void K_derivs(const float* __restrict__ blur, float* __restrict__ mag,
                         float* __restrict__ ang) {
    int j = blockIdx.x * 64 + threadIdx.x;
    int i = blockIdx.y * 4 + threadIdx.y;
    int p = blockIdx.z;
    const float* f = blur + (size_t)p * HW;
    float xmm = zp(f, i - 1, j - 1), xm0 = zp(f, i - 1, j), xmp = zp(f, i - 1, j + 1);
    float x0m = zp(f, i, j - 1), x0p = zp(f, i, j + 1);
    float xpm = zp(f, i + 1, j - 1), xp0 = zp(f, i + 1, j), xpp = zp(f, i + 1, j + 1);
    float ex = (xmp - xmm) + 2.0f * (x0p - x0m) + (xpp - xpm);
    float ey = (xpm + 2.0f * xp0 + xpp) - (xmm + 2.0f * xm0 + xmp);
    float e45 = -2.0f * xmm - xm0 - x0m + x0p + xp0 + 2.0f * xpp;
    float e135 = xm0 + 2.0f * xmp - x0m + x0p - 2.0f * xpm - xp0;
    float m = sqrtf(ex * ex + ey * ey + e45 * e45 + e135 * e135);
    float a = atan2f(ey, ex);
    a = fmodf(a, PI_F);
    if (a < 0.0f) a += PI_F;
    size_t idx = (size_t)p * HW + i * W + j;
    mag[idx] = m;
    ang[idx] = a;
}

__global__ void K_nms(const float* __restrict__ mag, const float* __restrict__ ang,
                      float* __restrict__ sup, float* __restrict__ pmax) {
    int j = blockIdx.x * 64 + threadIdx.x;
    int i = blockIdx.y * 4 + threadIdx.y;
    int p = blockIdx.z;
    const float* mp = mag + (size_t)p * HW;
    float m0 = mp[i * W + j];
    float a = ang[(size_t)p * HW + i * W + j];

    const float dirs[4] = {0.0f, 0.785398163397448f, 1.570796326794897f, 2.356194490192345f};
    float L[4];
    for (int t = 0; t < 4; t++) {
        float d = fabsf(a - dirs[t]);
        float mm = fminf(d, PI_F - d);
        L[t] = mm * (-100.0f);
    }
    float lm = fmaxf(fmaxf(L[0], L[1]), fmaxf(L[2], L[3]));
    float e0 = expf(L[0] - lm), e1 = expf(L[1] - lm), e2 = expf(L[2] - lm), e3 = expf(L[3] - lm);
    float esum = e0 + e1 + e2 + e3;
    float dw[4] = {e0 / esum, e1 / esum, e2 / esum, e3 / esum};

    int im = max(i - 1, 0), ip = min(i + 1, H - 1);
    int jm = max(j - 1, 0), jp = min(j + 1, W - 1);
    float n1s[4] = {mp[i * W + jm], mp[im * W + jm], mp[im * W + j], mp[im * W + jp]};
    float n2s[4] = {mp[i * W + jp], mp[ip * W + jp], mp[ip * W + j], mp[ip * W + jm]};

    float s = 0.0f;
    for (int t = 0; t < 4; t++) {
        float n1 = n1s[t], n2 = n2s[t];
        float mx3 = fmaxf(m0, fmaxf(n1, n2));
        float a0 = expf((m0 - mx3) * 10.0f);
        float a1 = expf((n1 - mx3) * 10.0f);
        float a2 = expf((n2 - mx3) * 10.0f);
        float sw = a0 / (a0 + a1 + a2);
        s += m0 * sw * dw[t];
    }
    sup[(size_t)p * HW + i * W + j] = s;

    // block-level max -> one private partial slot (no atomics)
    __shared__ float red[256];
    int tid = threadIdx.y * 64 + threadIdx.x;
    red[tid] = s;
    __syncthreads();
    for (int sft = 128; sft > 0; sft >>= 1) {
        if (tid < sft) red[tid] = fmaxf(red[tid], red[tid + sft]);
        __syncthreads();
    }
    if (tid == 0) {
        int bflat = (blockIdx.z * gridDim.y + blockIdx.y) * gridDim.x + blockIdx.x;
        pmax[bflat] = red[0];
    }
}

// fold 16384 partial maxima -> mx[0..1] (per set)
__global__ void K_redmax(const float* __restrict__ pmax, float* __restrict__ mx) {
    __shared__ float red[256];
    int t = threadIdx.x;
    for (int s = 0; s < 2; s++) {
        const float* base = pmax + s * (NBLK / 2);
        float v = -1e30f;
        for (int i = t; i < NBLK / 2; i += 256) v = fmaxf(v, base[i]);
        red[t] = v;
        __syncthreads();
        for (int sft = 128; sft > 0; sft >>= 1) {
            if (t < sft) red[t] = fmaxf(red[t], red[t + sft]);
            __syncthreads();
        }
        if (t == 0) mx[s] = red[0];
        __syncthreads();
    }
}

__global__ void K_result(const float* __restrict__ sup, const float* __restrict__ im1,
                         const float* __restrict__ im2, const float* __restrict__ lowv,
                         const float* __restrict__ highv, const float* __restrict__ wgtv,
                         const float* __restrict__ mx, float* __restrict__ res,
                         float* __restrict__ prmax, float* __restrict__ prmin) {
    int j = blockIdx.x * 64 + threadIdx.x;
    int i = blockIdx.y * 4 + threadIdx.y;
    int p = blockIdx.z;
    int s = p >> 3;
    float m = mx[s];
    float inv = 1.0f / ((m > 0.0f) ? m : 1.0f);
    float lo = lowv[s], hi = highv[s], wg = wgtv[s];
    const float* sp = sup + (size_t)p * HW;

    float sn0 = sp[i * W + j] * inv;
    float Sh0 = hsw(sn0 - hi);
    float Sl0 = hsw(sn0 - lo);
    float dil = 0.0f;
    for (int a = -1; a <= 1; a++) {
        int r = i + a;
        if (r < 0 || r >= H) continue;
        for (int b = -1; b <= 1; b++) {
            int c = j + b;
            if (c < 0 || c >= W) continue;
            dil += hsw(sp[r * W + c] * inv - hi);
        }
    }
    float pre = sn0 * (Sh0 + Sl0) + dil * Sl0 * (1.0f - Sh0);

    const float* op = plane_ptr(im1, im2, p);
    float exo, eyo;
    sobel_taps(op, i, j, exo, eyo);
    float sob = 0.5f * fabsf(exo) + 0.5f * fabsf(eyo);

    float r = (1.0f - wg) * pre + wg * sob;
    res[(size_t)p * HW + i * W + j] = r;

    __shared__ float rmx[256], rmn[256];
    int tid = threadIdx.y * 64 + threadIdx.x;
    rmx[tid] = r;
    rmn[tid] = r;
    __syncthreads();
    for (int sft = 128; sft > 0; sft >>= 1) {
        if (tid < sft) {
            rmx[tid] = fmaxf(rmx[tid], rmx[tid + sft]);
            rmn[tid] = fminf(rmn[tid], rmn[tid + sft]);
        }
        __syncthreads();
    }
    if (tid == 0) {
        int bflat = (blockIdx.z * gridDim.y + blockIdx.y) * gridDim.x + blockIdx.x;
        prmax[bflat] = rmx[0];
        prmin[bflat] = rmn[0];
    }
}

// fold result partial min/max -> rmaxv[0..1], rminv[0..1]
__global__ void K_redminmax(const float* __restrict__ prmax, const float* __restrict__ prmin,
                            float* __restrict__ rmaxv, float* __restrict__ rminv) {
    __shared__ float rmx[256], rmn[256];
    int t = threadIdx.x;
    for (int s = 0; s < 2; s++) {
        const float* bx = prmax + s * (NBLK / 2);
        const float* bn = prmin + s * (NBLK / 2);
        float vx = -1e30f, vn = 1e30f;
        for (int i = t; i < NBLK / 2; i += 256) {
            vx = fmaxf(vx, bx[i]);
            vn = fminf(vn, bn[i]);
        }
        rmx[t] = vx;
        rmn[t] = vn;
        __syncthreads();
        for (int sft = 128; sft > 0; sft >>= 1) {
            if (t < sft) {
                rmx[t] = fmaxf(rmx[t], rmx[t + sft]);
                rmn[t] = fminf(rmn[t], rmn[t + sft]);
            }
            __syncthreads();
        }
        if (t == 0) { rmaxv[s] = rmx[0]; rminv[s] = rmn[0]; }
        __syncthreads();
    }
}

__global__ void K_final(const float* __restrict__ res, const float* __restrict__ rmaxv,
                        const float* __restrict__ rminv, float* __restrict__ out) {
    int j = blockIdx.x * 64 + threadIdx.x;
    int i = blockIdx.y * 4 + threadIdx.y;
    int p = blockIdx.z;  // 0..7
    float mx1 = rmaxv[0], mn1 = rminv[0];
    float mx2 = rmaxv[1], mn2 = rminv[1];
    size_t idx = (size_t)p * HW + i * W + j;
    float r1 = res[idx];
    float r2 = res[(size_t)(p + PPS) * HW + i * W + j];
    float m1 = (r1 - mn1) / (mx1 - mn1);
    float m2 = (r2 - mn2) / (mx2 - mn2);
    out[idx] = m1 + m2 - 2.0f * m1 * m2;               // 1 - f
    out[(size_t)PPS * HW + idx] = m1;
    out[(size_t)2 * PPS * HW + idx] = m2;
}

}  // namespace

extern "C" void kernel_launch(void* const* d_in, const int* in_sizes, int n_in,
                              void* d_out, int out_size, void* d_ws, size_t ws_size,
                              hipStream_t stream) {
    const float* img1 = (const float*)d_in[0];
    const float* img2 = (const float*)d_in[1];
    const float* sg1 = (const float*)d_in[2];
    const float* ew1 = (const float*)d_in[3];
    const float* sg2 = (const float*)d_in[4];
    const float* ew2 = (const float*)d_in[5];
    float* out = (float*)d_out;

    float* A = (float*)d_ws;
    float* B = A + (size_t)NP * HW;
    float* C = B + (size_t)NP * HW;
    unsigned* hist = (unsigned*)(C + (size_t)NP * HW);
    unsigned* prefix = hist + NP * 256;
    int* krem = (int*)(prefix + NP);
    // scalar outputs of reduce kernels (separate from any atomic traffic)
    float* lowv = (float*)(krem + NP);
    float* highv = lowv + 2;
    float* wgtv = highv + 2;
    float* mx = wgtv + 2;
    float* rmaxv = mx + 2;
    float* rminv = rmaxv + 2;
    // per-block partials (one slot per block, no contention)
    float* pmax = rminv + 2;           // NBLK floats
    float* prmax = pmax + NBLK;        // NBLK floats
    float* prmin = prmax + NBLK;       // NBLK floats

    dim3 blk(64, 4, 1);
    dim3 grd(W / 64, H / 4, NP);
    dim3 grd8(W / 64, H / 4, PPS);
    dim3 mblk(256, 1, 1);
    dim3 mgrd(64, NP, 1);

    K_init<<<dim3(1), dim3(256), 0, stream>>>(hist, prefix, krem);

    // adaptive smoothing: 3 iterations, ping-pong  in->A, A->B, B->A
    K_w<<<grd, blk, 0, stream>>>(img1, img2, C);
    K_f<<<grd, blk, 0, stream>>>(img1, img2, C, A);
    K_w<<<grd, blk, 0, stream>>>(A, A + (size_t)PPS * HW, C);
    K_f<<<grd, blk, 0, stream>>>(A, A + (size_t)PPS * HW, C, B);
    K_w<<<grd, blk, 0, stream>>>(B, B + (size_t)PPS * HW, C);
    K_f<<<grd, blk, 0, stream>>>(B, B + (size_t)PPS * HW, C, A);   // blurred -> A

    // exact lower-median of sob(blurred) per plane via 4-pass radix select
    K_med0<<<mgrd, mblk, 0, stream>>>(A, B, hist);                  // sob -> B
    K_scan<<<dim3(1), dim3(256), 0, stream>>>(hist, prefix, krem, 24);
    K_medN<<<mgrd, mblk, 0, stream>>>(B, hist, prefix, 16);
    K_scan<<<dim3(1), dim3(256), 0, stream>>>(hist, prefix, krem, 16);
    K_medN<<<mgrd, mblk, 0, stream>>>(B, hist, prefix, 8);
    K_scan<<<dim3(1), dim3(256), 0, stream>>>(hist, prefix, krem, 8);
    K_medN<<<mgrd, mblk, 0, stream>>>(B, hist, prefix, 0);
    K_scan<<<dim3(1), dim3(256), 0, stream>>>(hist, prefix, krem, 0);
    K_thresh<<<dim3(1), dim3(64), 0, stream>>>(prefix, sg1, ew1, sg2, ew2, lowv, highv, wgtv);

    // gradients -> mag(B), ang(C); NMS -> sup(A) + partial max; reduce; result -> B
    K_derivs<<<grd, blk, 0, stream>>>(A, B, C);
    K_nms<<<grd, blk, 0, stream>>>(B, C, A, pmax);
    K_redmax<<<dim3(1), dim3(256), 0, stream>>>(pmax, mx);
    K_result<<<grd, blk, 0, stream>>>(A, img1, img2, lowv, highv, wgtv, mx, B, prmax, prmin);
    K_redminmax<<<dim3(1), dim3(256), 0, stream>>>(prmax, prmin, rmaxv, rminv);
    K_final<<<grd8, blk, 0, stream>>>(B, rmaxv, rminv, out);
}

// Round 3
// 191.455 us; speedup vs baseline: 4.0107x; 1.5991x over previous
//
#include <hip/hip_runtime.h>

namespace {

constexpr int H = 512;
constexpr int W = 512;
constexpr int HW = H * W;
constexpr int PPS = 8;    // planes per canny set
constexpr int NP = 16;    // total planes (2 sets x 8)
constexpr int TX = 64;    // tile width
constexpr int TY = 8;     // tile height
constexpr int NBLK = (W / TX) * (H / TY) * NP;   // 8192 tiled blocks total
constexpr float PI_F = 3.14159265358979323846f;

__device__ __forceinline__ float hsw(float x) {
    float t = fminf(fmaxf(x + 3.0f, 0.0f), 6.0f);
    return x * t * (1.0f / 6.0f);
}

__device__ __forceinline__ const float* plane_ptr(const float* s1, const float* s2, int p) {
    return (p < PPS) ? (s1 + (size_t)p * HW) : (s2 + (size_t)(p - PPS) * HW);
}

__device__ __forceinline__ float zp(const float* f, int i, int j) {
    return (i >= 0 && i < H && j >= 0 && j < W) ? f[i * W + j] : 0.0f;
}

__device__ __forceinline__ void sobel_taps(const float* f, int i, int j, float& ex, float& ey) {
    float xmm = zp(f, i - 1, j - 1), xm0 = zp(f, i - 1, j), xmp = zp(f, i - 1, j + 1);
    float x0m = zp(f, i, j - 1), x0p = zp(f, i, j + 1);
    float xpm = zp(f, i + 1, j - 1), xp0 = zp(f, i + 1, j), xpp = zp(f, i + 1, j + 1);
    ex = (xmp - xmm) + 2.0f * (x0p - x0m) + (xpp - xpm);
    ey = (xpm + 2.0f * xp0 + xpp) - (xmm + 2.0f * xm0 + xmp);
}

__global__ void K_init(unsigned* hist, unsigned* prefix, int* krem) {
    int t = threadIdx.x;
    for (int i = t; i < NP * 2048; i += 256) hist[i] = 0;
    if (t < NP) { prefix[t] = 0; krem[t] = (HW - 1) / 2; }
}

// One full adaptive-smoothing iteration, fused (w in LDS, exact clip semantics).
__global__ void K_smooth(const float* __restrict__ s1, const float* __restrict__ s2,
                         float* __restrict__ fout) {
    int p = blockIdx.z;
    const float* f = plane_ptr(s1, s2, p);
    int j0 = blockIdx.x * TX, i0 = blockIdx.y * TY;
    __shared__ float fs[TY + 4][TX + 4];   // f[clip(i0-2+y)][clip(j0-2+x)]
    __shared__ float ws[TY + 2][TX + 2];   // w(clip(i0-1+y), clip(j0-1+x))
    int tid = threadIdx.y * 64 + threadIdx.x;

    for (int e = tid; e < (TY + 4) * (TX + 4); e += 256) {
        int y = e / (TX + 4), x = e % (TX + 4);
        int gi = min(max(i0 - 2 + y, 0), H - 1);
        int gj = min(max(j0 - 2 + x, 0), W - 1);
        fs[y][x] = f[gi * W + gj];
    }
    __syncthreads();

    for (int e = tid; e < (TY + 2) * (TX + 2); e += 256) {
        int y = e / (TX + 2), x = e % (TX + 2);
        int r = min(max(i0 - 1 + y, 0), H - 1);   // w evaluated at CLIPPED coords
        int c = min(max(j0 - 1 + x, 0), W - 1);
        int yf = r - (i0 - 2), xf = c - (j0 - 2);
        float gx = 0.5f * (fs[yf + 1][xf] - fs[yf - 1][xf]);
        float gy = 0.5f * (fs[yf][xf + 1] - fs[yf][xf - 1]);
        ws[y][x] = __expf(-(gx * gx + gy * gy) * (1.0f / 200.0f));
    }
    __syncthreads();

    for (int q = 0; q < TY / 4; q++) {
        int yl = threadIdx.y + q * 4;
        int xl = threadIdx.x;
        float num = 0.0f, den = 0.0f;
        for (int a = -1; a <= 1; a++) {
            for (int b = -1; b <= 1; b++) {
                float wv = ws[yl + 1 + a][xl + 1 + b];
                float fv = fs[yl + 2 + a][xl + 2 + b];
                num += fv * wv;
                den += wv;
            }
        }
        fout[(size_t)p * HW + (i0 + yl) * W + (j0 + xl)] = num / fmaxf(den, 1e-8f);
    }
}

// median pass 0: compute sob(blurred), store it, histogram top 11 bits
__global__ void K_med0(const float* __restrict__ blur, float* __restrict__ sob,
                       unsigned* __restrict__ hist) {
    __shared__ unsigned sh[2048];
    int t = threadIdx.x;
    int p = blockIdx.y;
    for (int i = t; i < 2048; i += 256) sh[i] = 0;
    __syncthreads();
    const float* f = blur + (size_t)p * HW;
    int base = blockIdx.x * 4096;
    for (int r = 0; r < 16; r++) {
        int ij = base + r * 256 + t;
        int i = ij >> 9, j = ij & 511;
        float ex, ey;
        sobel_taps(f, i, j, ex, ey);
        float s = 0.5f * fabsf(ex) + 0.5f * fabsf(ey);
        sob[(size_t)p * HW + ij] = s;
        atomicAdd(&sh[__float_as_uint(s) >> 21], 1u);
    }
    __syncthreads();
    for (int i = t; i < 2048; i += 256)
        if (sh[i]) atomicAdd(&hist[p * 2048 + i], sh[i]);
}

// median passes 1..2: filter by prefix, histogram next bits
__global__ void K_medN(const float* __restrict__ sob, unsigned* __restrict__ hist,
                       const unsigned* __restrict__ prefix, unsigned himask,
                       int shift, unsigned binmask) {
    __shared__ unsigned sh[2048];
    int t = threadIdx.x;
    int p = blockIdx.y;
    for (int i = t; i < 2048; i += 256) sh[i] = 0;
    __syncthreads();
    unsigned pfx = prefix[p];
    int base = blockIdx.x * 4096;
    for (int r = 0; r < 16; r++) {
        int ij = base + r * 256 + t;
        unsigned b = __float_as_uint(sob[(size_t)p * HW + ij]);
        if ((b & himask) == pfx) atomicAdd(&sh[(b >> shift) & binmask], 1u);
    }
    __syncthreads();
    for (int i = t; i < 2048; i += 256)
        if (sh[i]) atomicAdd(&hist[p * 2048 + i], sh[i]);
}

// one block per plane: scan nbins-bin histogram, pick bucket, update prefix/krem
__global__ void K_scan(unsigned* hist, unsigned* prefix, int* krem, int shift, int nbins) {
    __shared__ unsigned sums[256];
    int p = blockIdx.x;
    unsigned* hp = hist + p * 2048;
    int t = threadIdx.x;
    int per = nbins / 256;
    unsigned s = 0;
    for (int q = 0; q < per; q++) s += hp[t * per + q];
    sums[t] = s;
    __syncthreads();
    for (int off = 1; off < 256; off <<= 1) {
        unsigned v = (t >= off) ? sums[t - off] : 0u;
        __syncthreads();
        sums[t] += v;
        __syncthreads();
    }
    int k = krem[p];
    __syncthreads();   // everyone has read k before the winner rewrites it
    unsigned base = (t == 0) ? 0u : sums[t - 1];
    if ((int)base <= k && k < (int)sums[t]) {
        int cum = (int)base;
        int b = t * per;
        for (int q = 0; q < per; q++) {
            int c = (int)hp[t * per + q];
            if (cum + c > k) { b = t * per + q; break; }
            cum += c;
        }
        prefix[p] |= ((unsigned)b) << shift;
        krem[p] = k - cum;
    }
    __syncthreads();
    for (int q = t; q < 2048; q += 256) hp[q] = 0;
}

__global__ void K_thresh(const unsigned* prefix, const float* sg1, const float* ew1,
                         const float* sg2, const float* ew2,
                         float* lowv, float* highv, float* wgtv) {
    int s = threadIdx.x;
    if (s < 2) {
        float med = 0.0f;
        for (int p = 0; p < PPS; p++) med += __uint_as_float(prefix[s * PPS + p]);
        med *= 0.125f;
        float sgin = (s == 0) ? sg1[0] : sg2[0];
        float ewin = (s == 0) ? ew1[0] : ew2[0];
        float sigm = 1.0f / (1.0f + expf(-sgin));
        float sig = 1.0f - sigm;
        lowv[s] = fminf(fmaxf((1.0f - sig) * med, 0.001f), 1.0f);
        highv[s] = fminf(fmaxf((1.0f + sig) * med, 0.001f), 1.0f);
        wgtv[s] = 1.0f / (1.0f + expf(-ewin));
    }
}

// fused 4-direction derivatives + NMS (mag tile in LDS at clipped coords)
__global__ void K_dnms(const float* __restrict__ blur, float* __restrict__ sup,
                       float* __restrict__ pmax) {
    int p = blockIdx.z;
    const float* f = blur + (size_t)p * HW;
    int j0 = blockIdx.x * TX, i0 = blockIdx.y * TY;
    __shared__ float ms[TY + 2][TX + 2];
    __shared__ float exs[TY][TX], eys[TY][TX];
    int tid = threadIdx.y * 64 + threadIdx.x;

    for (int e = tid; e < (TY + 2) * (TX + 2); e += 256) {
        int y = e / (TX + 2), x = e % (TX + 2);
        int r = min(max(i0 - 1 + y, 0), H - 1);   // replicate-pad via clip
        int c = min(max(j0 - 1 + x, 0), W - 1);
        float xmm = zp(f, r - 1, c - 1), xm0 = zp(f, r - 1, c), xmp = zp(f, r - 1, c + 1);
        float x0m = zp(f, r, c - 1), x0p = zp(f, r, c + 1);
        float xpm = zp(f, r + 1, c - 1), xp0 = zp(f, r + 1, c), xpp = zp(f, r + 1, c + 1);
        float ex = (xmp - xmm) + 2.0f * (x0p - x0m) + (xpp - xpm);
        float ey = (xpm + 2.0f * xp0 + xpp) - (xmm + 2.0f * xm0 + xmp);
        float e45 = -2.0f * xmm - xm0 - x0m + x0p + xp0 + 2.0f * xpp;
        float e135 = xm0 + 2.0f * xmp - x0m + x0p - 2.0f * xpm - xp0;
        ms[y][x] = sqrtf(ex * ex + ey * ey + e45 * e45 + e135 * e135);
        if (y >= 1 && y <= TY && x >= 1 && x <= TX) {
            exs[y - 1][x - 1] = ex;
            eys[y - 1][x - 1] = ey;
        }
    }
    __syncthreads();

    float bmax = 0.0f;   // sup >= 0
    for (int q = 0; q < TY / 4; q++) {
        int yl = threadIdx.y + q * 4;
        int xl = threadIdx.x;
        float ex = exs[yl][xl], ey = eys[yl][xl];
        float a = atan2f(ey, ex);
        a = fmodf(a, PI_F);
        if (a < 0.0f) a += PI_F;

        const float dirs[4] = {0.0f, 0.785398163397448f, 1.570796326794897f, 2.356194490192345f};
        float L[4];
        for (int t = 0; t < 4; t++) {
            float d = fabsf(a - dirs[t]);
            L[t] = fminf(d, PI_F - d) * (-100.0f);
        }
        float lm = fmaxf(fmaxf(L[0], L[1]), fmaxf(L[2], L[3]));
        float e0 = __expf(L[0] - lm), e1 = __expf(L[1] - lm);
        float e2 = __expf(L[2] - lm), e3 = __expf(L[3] - lm);
        float einv = __fdividef(1.0f, e0 + e1 + e2 + e3);
        float dw[4] = {e0 * einv, e1 * einv, e2 * einv, e3 * einv};

        float m0 = ms[yl + 1][xl + 1];
        float n1s[4] = {ms[yl + 1][xl], ms[yl][xl], ms[yl][xl + 1], ms[yl][xl + 2]};
        float n2s[4] = {ms[yl + 1][xl + 2], ms[yl + 2][xl + 2], ms[yl + 2][xl + 1], ms[yl + 2][xl]};

        float s = 0.0f;
        for (int t = 0; t < 4; t++) {
            float n1 = n1s[t], n2 = n2s[t];
            float mx3 = fmaxf(m0, fmaxf(n1, n2));
            float a0 = __expf((m0 - mx3) * 10.0f);
            float a1 = __expf((n1 - mx3) * 10.0f);
            float a2 = __expf((n2 - mx3) * 10.0f);
            float sw = __fdividef(a0, a0 + a1 + a2);
            s += m0 * sw * dw[t];
        }
        sup[(size_t)p * HW + (i0 + yl) * W + (j0 + xl)] = s;
        bmax = fmaxf(bmax, s);
    }

    __shared__ float red[256];
    red[tid] = bmax;
    __syncthreads();
    for (int sft = 128; sft > 0; sft >>= 1) {
        if (tid < sft) red[tid] = fmaxf(red[tid], red[tid + sft]);
        __syncthreads();
    }
    if (tid == 0) {
        int bflat = (blockIdx.z * gridDim.y + blockIdx.y) * gridDim.x + blockIdx.x;
        pmax[bflat] = red[0];
    }
}

__global__ void K_redmax(const float* __restrict__ pmax, float* __restrict__ mx) {
    __shared__ float red[256];
    int t = threadIdx.x;
    for (int s = 0; s < 2; s++) {
        const float* base = pmax + s * (NBLK / 2);
        float v = -1e30f;
        for (int i = t; i < NBLK / 2; i += 256) v = fmaxf(v, base[i]);
        red[t] = v;
        __syncthreads();
        for (int sft = 128; sft > 0; sft >>= 1) {
            if (t < sft) red[t] = fmaxf(red[t], red[t + sft]);
            __syncthreads();
        }
        if (t == 0) mx[s] = red[0];
        __syncthreads();
    }
}

// hysteresis combine + dilation (h tile in LDS) + sobel(original) blend
__global__ void K_result(const float* __restrict__ sup, const float* __restrict__ im1,
                         const float* __restrict__ im2, const float* __restrict__ lowv,
                         const float* __restrict__ highv, const float* __restrict__ wgtv,
                         const float* __restrict__ mx, float* __restrict__ res,
                         float* __restrict__ prmax, float* __restrict__ prmin) {
    int p = blockIdx.z;
    int s = p >> 3;
    float m = mx[s];
    float inv = 1.0f / ((m > 0.0f) ? m : 1.0f);
    float lo = lowv[s], hi = highv[s], wg = wgtv[s];
    const float* sp = sup + (size_t)p * HW;
    int j0 = blockIdx.x * TX, i0 = blockIdx.y * TY;
    __shared__ float hs[TY + 2][TX + 2];   // hsw(sup_norm - hi), 0 outside image (zero-pad)
    __shared__ float ssn[TY][TX];          // normalized sup, interior
    int tid = threadIdx.y * 64 + threadIdx.x;

    for (int e = tid; e < (TY + 2) * (TX + 2); e += 256) {
        int y = e / (TX + 2), x = e % (TX + 2);
        int gi = i0 - 1 + y, gj = j0 - 1 + x;
        float h = 0.0f;
        if (gi >= 0 && gi < H && gj >= 0 && gj < W) {
            float sv = sp[gi * W + gj] * inv;
            h = hsw(sv - hi);
            if (y >= 1 && y <= TY && x >= 1 && x <= TX) ssn[y - 1][x - 1] = sv;
        }
        hs[y][x] = h;
    }
    __syncthreads();

    float bmx = -1e30f, bmn = 1e30f;
    for (int q = 0; q < TY / 4; q++) {
        int yl = threadIdx.y + q * 4;
        int xl = threadIdx.x;
        float sn0 = ssn[yl][xl];
        float Sh0 = hs[yl + 1][xl + 1];
        float Sl0 = hsw(sn0 - lo);
        float dil = 0.0f;
        for (int a = 0; a < 3; a++)
            for (int b = 0; b < 3; b++) dil += hs[yl + a][xl + b];
        float pre = sn0 * (Sh0 + Sl0) + dil * Sl0 * (1.0f - Sh0);

        const float* op = plane_ptr(im1, im2, p);
        float exo, eyo;
        sobel_taps(op, i0 + yl, j0 + xl, exo, eyo);
        float sob = 0.5f * fabsf(exo) + 0.5f * fabsf(eyo);

        float r = (1.0f - wg) * pre + wg * sob;
        res[(size_t)p * HW + (i0 + yl) * W + (j0 + xl)] = r;
        bmx = fmaxf(bmx, r);
        bmn = fminf(bmn, r);
    }

    __shared__ float rmx[256], rmn[256];
    rmx[tid] = bmx;
    rmn[tid] = bmn;
    __syncthreads();
    for (int sft = 128; sft > 0; sft >>= 1) {
        if (tid < sft) {
            rmx[tid] = fmaxf(rmx[tid], rmx[tid + sft]);
            rmn[tid] = fminf(rmn[tid], rmn[tid + sft]);
        }
        __syncthreads();
    }
    if (tid == 0) {
        int bflat = (blockIdx.z * gridDim.y + blockIdx.y) * gridDim.x + blockIdx.x;
        prmax[bflat] = rmx[0];
        prmin[bflat] = rmn[0];
    }
}

__global__ void K_redminmax(const float* __restrict__ prmax, const float* __restrict__ prmin,
                            float* __restrict__ rmaxv, float* __restrict__ rminv) {
    __shared__ float rmx[256], rmn[256];
    int t = threadIdx.x;
    for (int s = 0; s < 2; s++) {
        const float* bx = prmax + s * (NBLK / 2);
        const float* bn = prmin + s * (NBLK / 2);
        float vx = -1e30f, vn = 1e30f;
        for (int i = t; i < NBLK / 2; i += 256) {
            vx = fmaxf(vx, bx[i]);
            vn = fminf(vn, bn[i]);
        }
        rmx[t] = vx;
        rmn[t] = vn;
        __syncthreads();
        for (int sft = 128; sft > 0; sft >>= 1) {
            if (t < sft) {
                rmx[t] = fmaxf(rmx[t], rmx[t + sft]);
                rmn[t] = fminf(rmn[t], rmn[t + sft]);
            }
            __syncthreads();
        }
        if (t == 0) { rmaxv[s] = rmx[0]; rminv[s] = rmn[0]; }
        __syncthreads();
    }
}

__global__ void K_final(const float* __restrict__ res, const float* __restrict__ rmaxv,
                        const float* __restrict__ rminv, float* __restrict__ out) {
    int j = blockIdx.x * 64 + threadIdx.x;
    int i = blockIdx.y * 4 + threadIdx.y;
    int p = blockIdx.z;  // 0..7
    float mx1 = rmaxv[0], mn1 = rminv[0];
    float mx2 = rmaxv[1], mn2 = rminv[1];
    size_t idx = (size_t)p * HW + i * W + j;
    float r1 = res[idx];
    float r2 = res[(size_t)(p + PPS) * HW + i * W + j];
    float m1 = (r1 - mn1) / (mx1 - mn1);
    float m2 = (r2 - mn2) / (mx2 - mn2);
    out[idx] = m1 + m2 - 2.0f * m1 * m2;               // 1 - f
    out[(size_t)PPS * HW + idx] = m1;
    out[(size_t)2 * PPS * HW + idx] = m2;
}

}  // namespace

extern "C" void kernel_launch(void* const* d_in, const int* in_sizes, int n_in,
                              void* d_out, int out_size, void* d_ws, size_t ws_size,
                              hipStream_t stream) {
    const float* img1 = (const float*)d_in[0];
    const float* img2 = (const float*)d_in[1];
    const float* sg1 = (const float*)d_in[2];
    const float* ew1 = (const float*)d_in[3];
    const float* sg2 = (const float*)d_in[4];
    const float* ew2 = (const float*)d_in[5];
    float* out = (float*)d_out;

    float* A = (float*)d_ws;
    float* B = A + (size_t)NP * HW;
    float* C = B + (size_t)NP * HW;
    unsigned* hist = (unsigned*)(C + (size_t)NP * HW);   // NP*2048
    unsigned* prefix = hist + NP * 2048;
    int* krem = (int*)(prefix + NP);
    float* lowv = (float*)(krem + NP);
    float* highv = lowv + 2;
    float* wgtv = highv + 2;
    float* mx = wgtv + 2;
    float* rmaxv = mx + 2;
    float* rminv = rmaxv + 2;
    float* pmax = rminv + 2;           // NBLK
    float* prmax = pmax + NBLK;        // NBLK
    float* prmin = prmax + NBLK;       // NBLK

    dim3 blk(64, 4, 1);
    dim3 grdT(W / TX, H / TY, NP);     // tiled kernels (2 rows/thread)
    dim3 grdF(W / 64, H / 4, PPS);     // final
    dim3 mblk(256, 1, 1);
    dim3 mgrd(64, NP, 1);

    K_init<<<dim3(1), dim3(256), 0, stream>>>(hist, prefix, krem);

    // adaptive smoothing: 3 fused iterations  in->A, A->B, B->A
    K_smooth<<<grdT, blk, 0, stream>>>(img1, img2, A);
    K_smooth<<<grdT, blk, 0, stream>>>(A, A + (size_t)PPS * HW, B);
    K_smooth<<<grdT, blk, 0, stream>>>(B, B + (size_t)PPS * HW, A);   // blurred -> A

    // exact lower-median of sob(blurred): 3-pass radix select (11/11/10 bits)
    K_med0<<<mgrd, mblk, 0, stream>>>(A, B, hist);                    // sob -> B
    K_scan<<<dim3(NP), mblk, 0, stream>>>(hist, prefix, krem, 21, 2048);
    K_medN<<<mgrd, mblk, 0, stream>>>(B, hist, prefix, 0xFFE00000u, 10, 2047u);
    K_scan<<<dim3(NP), mblk, 0, stream>>>(hist, prefix, krem, 10, 2048);
    K_medN<<<mgrd, mblk, 0, stream>>>(B, hist, prefix, 0xFFFFFC00u, 0, 1023u);
    K_scan<<<dim3(NP), mblk, 0, stream>>>(hist, prefix, krem, 0, 1024);
    K_thresh<<<dim3(1), dim3(64), 0, stream>>>(prefix, sg1, ew1, sg2, ew2, lowv, highv, wgtv);

    // fused derivs+NMS: blur(A) -> sup(C); reduce max; result -> B; final -> out
    K_dnms<<<grdT, blk, 0, stream>>>(A, C, pmax);
    K_redmax<<<dim3(1), mblk, 0, stream>>>(pmax, mx);
    K_result<<<grdT, blk, 0, stream>>>(C, img1, img2, lowv, highv, wgtv, mx, B, prmax, prmin);
    K_redminmax<<<dim3(1), mblk, 0, stream>>>(prmax, prmin, rmaxv, rminv);
    K_final<<<grdF, blk, 0, stream>>>(B, rmaxv, rminv, out);
}